// Round 3
// baseline (912.144 us; speedup 1.0000x reference)
//
#include <hip/hip_runtime.h>

#define B_   2
#define S_   2048
#define H_   32
#define D_   64
#define HID_ 2048

typedef unsigned short ushort_t;
typedef __attribute__((ext_vector_type(8))) short short8;
typedef __attribute__((ext_vector_type(4))) float floatx4;

__device__ __forceinline__ float bf2f(ushort_t u) {
    union { unsigned int i; float f; } v; v.i = ((unsigned int)u) << 16; return v.f;
}
__device__ __forceinline__ ushort_t f2bf(float f) {
    union { float f; unsigned int i; } v; v.f = f;
    unsigned int x = v.i;
    unsigned int r = x + 0x7fffu + ((x >> 16) & 1u);
    return (ushort_t)(r >> 16);
}

// fp32 -> bf16 cast, 8 elements/thread.
__global__ __launch_bounds__(256) void cast_f32_bf16(const float* __restrict__ in,
                                                     ushort_t* __restrict__ out,
                                                     int n8) {
    int i = blockIdx.x * 256 + threadIdx.x;
    if (i >= n8) return;
    const float4* p = (const float4*)(in + (size_t)i * 8);
    float4 a = p[0], b = p[1];
    short8 o;
    o[0] = (short)f2bf(a.x); o[1] = (short)f2bf(a.y);
    o[2] = (short)f2bf(a.z); o[3] = (short)f2bf(a.w);
    o[4] = (short)f2bf(b.x); o[5] = (short)f2bf(b.y);
    o[6] = (short)f2bf(b.z); o[7] = (short)f2bf(b.w);
    *(short8*)(out + (size_t)i * 8) = o;
}

// C = A @ B^T.  A: M x K (bf16 row-major), B: N x K (bf16 row-major).
// C: M x N, bf16 (OF32=false) or fp32 (OF32=true).
// 128x128 tile, 4 waves, each wave a 64x64 quadrant as 4x4 MFMA 16x16x32 tiles.
template <bool OF32>
__global__ __launch_bounds__(256) void gemm_bt(const ushort_t* __restrict__ A,
                                               const ushort_t* __restrict__ Bm,
                                               void* __restrict__ Cv,
                                               int M, int N, int K) {
    __shared__ ushort_t lA[128][40];
    __shared__ ushort_t lB[128][40];
    const int tid  = threadIdx.x;
    const int lane = tid & 63, wave = tid >> 6;
    const int quad = lane >> 4, l16 = lane & 15;
    const int wm = wave >> 1, wn = wave & 1;
    const int m0 = blockIdx.y * 128, n0 = blockIdx.x * 128;
    const int ldRow = tid >> 1;
    const int ldSeg = (tid & 1) * 16;

    floatx4 acc[4][4];
#pragma unroll
    for (int i = 0; i < 4; i++)
#pragma unroll
        for (int j = 0; j < 4; j++) acc[i][j] = (floatx4){0.f, 0.f, 0.f, 0.f};

    for (int k0 = 0; k0 < K; k0 += 32) {
        const short8* ga = (const short8*)(A + (size_t)(m0 + ldRow) * K + k0 + ldSeg);
        const short8* gb = (const short8*)(Bm + (size_t)(n0 + ldRow) * K + k0 + ldSeg);
        short8 a0 = ga[0], a1 = ga[1];
        short8 b0 = gb[0], b1 = gb[1];
        *(short8*)&lA[ldRow][ldSeg]     = a0;
        *(short8*)&lA[ldRow][ldSeg + 8] = a1;
        *(short8*)&lB[ldRow][ldSeg]     = b0;
        *(short8*)&lB[ldRow][ldSeg + 8] = b1;
        __syncthreads();

        short8 aF[4], bF[4];
#pragma unroll
        for (int mi = 0; mi < 4; mi++) aF[mi] = *(const short8*)&lA[wm * 64 + mi * 16 + l16][quad * 8];
#pragma unroll
        for (int ni = 0; ni < 4; ni++) bF[ni] = *(const short8*)&lB[wn * 64 + ni * 16 + l16][quad * 8];
#pragma unroll
        for (int mi = 0; mi < 4; mi++)
#pragma unroll
            for (int ni = 0; ni < 4; ni++)
                acc[mi][ni] = __builtin_amdgcn_mfma_f32_16x16x32_bf16(aF[mi], bF[ni], acc[mi][ni], 0, 0, 0);
        __syncthreads();
    }

#pragma unroll
    for (int mi = 0; mi < 4; mi++)
#pragma unroll
        for (int ni = 0; ni < 4; ni++)
#pragma unroll
            for (int r = 0; r < 4; r++) {
                int row = m0 + wm * 64 + mi * 16 + quad * 4 + r;
                int col = n0 + wn * 64 + ni * 16 + l16;
                if (OF32) ((float*)Cv)[(size_t)row * N + col] = acc[mi][ni][r];
                else      ((ushort_t*)Cv)[(size_t)row * N + col] = f2bf(acc[mi][ni][r]);
            }
}

// qkv: (B,S,H,3D) bf16 -> q_rot, k_rot as (B,H,S,D) bf16.
__global__ __launch_bounds__(256) void rope_qk(const ushort_t* __restrict__ qkv,
                                               const int* __restrict__ pos,
                                               ushort_t* __restrict__ qr,
                                               ushort_t* __restrict__ kr) {
    int idx = blockIdx.x * 256 + threadIdx.x;   // (b,h,s,d): d fastest
    int d = idx & 63;
    int s = (idx >> 6) & 2047;
    int h = (idx >> 17) & 31;
    int b = idx >> 22;
    size_t qbase = ((size_t)(b * S_ + s)) * (3 * H_ * D_) + h * (3 * D_);
    int i  = d & 31;
    int d2 = d ^ 32;
    float x   = bf2f(qkv[qbase + d]);
    float xp  = bf2f(qkv[qbase + d2]);
    float kx  = bf2f(qkv[qbase + 64 + d]);
    float kxp = bf2f(qkv[qbase + 64 + d2]);
    int   p   = pos[b * S_ + s];
    float inv = 1.0f / powf(10000.0f, (float)(2 * i) / 64.0f);
    float t   = (float)p * inv;
    float c = cosf(t), sn = sinf(t);
    float rq = (d < 32) ? -xp : xp;
    float rk = (d < 32) ? -kxp : kxp;
    float qo = x * c + rq * sn;
    float ko = kx * c + rk * sn;
    size_t o = ((size_t)(b * H_ + h) * S_ + s) * D_ + d;
    qr[o] = f2bf(qo);
    kr[o] = f2bf(ko);
}

// v transpose: qkv (B,S,H,3D) -> vt (B,H,D,S).
__global__ __launch_bounds__(256) void v_trans(const ushort_t* __restrict__ qkv,
                                               ushort_t* __restrict__ vt) {
    int idx = blockIdx.x * 256 + threadIdx.x;   // (b,h,d,s): s fastest
    int s = idx & 2047;
    int d = (idx >> 11) & 63;
    int h = (idx >> 17) & 31;
    int b = idx >> 22;
    vt[idx] = qkv[((size_t)(b * S_ + s)) * (3 * H_ * D_) + h * (3 * D_) + 128 + d];
}

// Flash attention. qr,kr: (B,H,S,D); vt: (B,H,D,S); mask: (B,1,S,S) int32 (bool promoted).
// ctx out: (B,S,H*D) bf16. 4 waves/block, each wave owns 16 q rows.
__global__ __launch_bounds__(256) void attn_kernel(const ushort_t* __restrict__ qr,
                                                   const ushort_t* __restrict__ kr,
                                                   const ushort_t* __restrict__ vt,
                                                   const int* __restrict__ mask,
                                                   ushort_t* __restrict__ ctx) {
    __shared__ ushort_t lds_p[4][16][72];
    const int tid  = threadIdx.x;
    const int wave = tid >> 6, lane = tid & 63;
    const int quad = lane >> 4, l16 = lane & 15;
    const int b = blockIdx.z, h = blockIdx.y;
    const int q0 = blockIdx.x * 64 + wave * 16;
    const size_t headBase = ((size_t)(b * H_ + h)) * S_ * D_;
    const size_t maskBase = (size_t)b * S_ * S_;

    short8 qf[2];
#pragma unroll
    for (int ks = 0; ks < 2; ks++)
        qf[ks] = *(const short8*)(qr + headBase + (size_t)(q0 + l16) * D_ + ks * 32 + quad * 8);

    float m_st[4], l_st[4];
    floatx4 o[4];
#pragma unroll
    for (int r = 0; r < 4; r++) { m_st[r] = -1e30f; l_st[r] = 0.f; }
#pragma unroll
    for (int t = 0; t < 4; t++) o[t] = (floatx4){0.f, 0.f, 0.f, 0.f};

    for (int k0 = 0; k0 < S_; k0 += 64) {
        short8 kf[4][2];
#pragma unroll
        for (int t = 0; t < 4; t++)
#pragma unroll
            for (int ks = 0; ks < 2; ks++)
                kf[t][ks] = *(const short8*)(kr + headBase + (size_t)(k0 + t * 16 + l16) * D_ + ks * 32 + quad * 8);

        floatx4 sc[4];
#pragma unroll
        for (int t = 0; t < 4; t++) sc[t] = (floatx4){0.f, 0.f, 0.f, 0.f};
#pragma unroll
        for (int t = 0; t < 4; t++)
#pragma unroll
            for (int ks = 0; ks < 2; ks++)
                sc[t] = __builtin_amdgcn_mfma_f32_16x16x32_bf16(qf[ks], kf[t][ks], sc[t], 0, 0, 0);

        float p[4][4];
#pragma unroll
        for (int t = 0; t < 4; t++)
#pragma unroll
            for (int r = 0; r < 4; r++) {
                float v = sc[t][r] * 0.125f;
                int qrow = q0 + quad * 4 + r;
                int kcol = k0 + t * 16 + l16;
                if (mask[maskBase + (size_t)qrow * S_ + kcol] != 0) v = -10000.0f;
                p[t][r] = v;
            }

        float alpha[4];
#pragma unroll
        for (int r = 0; r < 4; r++) {
            float rm = fmaxf(fmaxf(p[0][r], p[1][r]), fmaxf(p[2][r], p[3][r]));
#pragma unroll
            for (int off = 1; off < 16; off <<= 1) rm = fmaxf(rm, __shfl_xor(rm, off, 64));
            float mn = fmaxf(m_st[r], rm);
            alpha[r] = __expf(m_st[r] - mn);
            m_st[r] = mn;
            float rs = 0.f;
#pragma unroll
            for (int t = 0; t < 4; t++) { p[t][r] = __expf(p[t][r] - mn); rs += p[t][r]; }
#pragma unroll
            for (int off = 1; off < 16; off <<= 1) rs += __shfl_xor(rs, off, 64);
            l_st[r] = l_st[r] * alpha[r] + rs;
        }
#pragma unroll
        for (int t = 0; t < 4; t++)
#pragma unroll
            for (int r = 0; r < 4; r++) o[t][r] *= alpha[r];

#pragma unroll
        for (int t = 0; t < 4; t++)
#pragma unroll
            for (int r = 0; r < 4; r++)
                lds_p[wave][quad * 4 + r][t * 16 + l16] = f2bf(p[t][r]);
        __syncthreads();

        short8 pf[2];
#pragma unroll
        for (int ks = 0; ks < 2; ks++)
            pf[ks] = *(const short8*)&lds_p[wave][l16][ks * 32 + quad * 8];

#pragma unroll
        for (int t = 0; t < 4; t++)
#pragma unroll
            for (int ks = 0; ks < 2; ks++) {
                short8 vf = *(const short8*)(vt + headBase + (size_t)(t * 16 + l16) * S_ + k0 + ks * 32 + quad * 8);
                o[t] = __builtin_amdgcn_mfma_f32_16x16x32_bf16(pf[ks], vf, o[t], 0, 0, 0);
            }
        __syncthreads();
    }

#pragma unroll
    for (int t = 0; t < 4; t++)
#pragma unroll
        for (int r = 0; r < 4; r++) {
            int srow = q0 + quad * 4 + r;
            float val = o[t][r] / l_st[r];
            ctx[((size_t)(b * S_) + srow) * (H_ * D_) + h * D_ + t * 16 + l16] = f2bf(val);
        }
}

extern "C" void kernel_launch(void* const* d_in, const int* in_sizes, int n_in,
                              void* d_out, int out_size, void* d_ws, size_t ws_size,
                              hipStream_t stream) {
    const float* hidden          = (const float*)d_in[0];      // fp32 (B,S,HID)
    const int* mask              = (const int*)d_in[1];        // bool -> int32
    const int* pos               = (const int*)d_in[2];        // int32
    const float* Wqkv            = (const float*)d_in[3];      // fp32 (3HD, HID)
    const float* Wo              = (const float*)d_in[4];      // fp32 (HID, HD)
    float* out                   = (float*)d_out;              // fp32 (B,S,HID)

    char* ws = (char*)d_ws;
    // layout (bytes):
    //   qkv     [0,          50331648)   bf16 (B,S,H,3D)
    //   Wo_bf   [50331648,   58720256)
    //   hid_bf  [58720256,   75497472)   dead after QKV gemm
    //   Wqkv_bf [75497472,  100663296)   dead after QKV gemm
    //   q_r     [58720256,   75497472)   reuse hid_bf
    //   k_r     [75497472,   92274688)   reuse Wqkv_bf (front)
    //   v_t     [92274688,  109051904)
    //   ctx     [0,          16777216)   reuse qkv (dead after rope/v_trans)
    ushort_t* qkv     = (ushort_t*)(ws);
    ushort_t* Wo_bf   = (ushort_t*)(ws + 50331648);
    ushort_t* hid_bf  = (ushort_t*)(ws + 58720256);
    ushort_t* Wqkv_bf = (ushort_t*)(ws + 75497472);
    ushort_t* q_r     = (ushort_t*)(ws + 58720256);
    ushort_t* k_r     = (ushort_t*)(ws + 75497472);
    ushort_t* v_t     = (ushort_t*)(ws + 92274688);
    ushort_t* ctx     = (ushort_t*)(ws);

    // 0. casts fp32 -> bf16
    {
        int n8 = (B_ * S_ * HID_) / 8;                 // 1,048,576
        cast_f32_bf16<<<n8 / 256, 256, 0, stream>>>(hidden, hid_bf, n8);
        n8 = (3 * H_ * D_ * HID_) / 8;                 // 1,572,864
        cast_f32_bf16<<<n8 / 256, 256, 0, stream>>>(Wqkv, Wqkv_bf, n8);
        n8 = (HID_ * H_ * D_) / 8;                     // 524,288
        cast_f32_bf16<<<n8 / 256, 256, 0, stream>>>(Wo, Wo_bf, n8);
    }

    // 1. QKV projection: (B*S, HID) @ W_qkv^T -> (B*S, 3*H*D) bf16
    gemm_bt<false><<<dim3((3 * H_ * D_) / 128, (B_ * S_) / 128), 256, 0, stream>>>(
        hid_bf, Wqkv_bf, qkv, B_ * S_, 3 * H_ * D_, HID_);

    // 2. RoPE (q,k) + v transpose
    int nElem = B_ * H_ * S_ * D_;
    rope_qk<<<nElem / 256, 256, 0, stream>>>(qkv, pos, q_r, k_r);
    v_trans<<<nElem / 256, 256, 0, stream>>>(qkv, v_t);

    // 3. Flash attention -> ctx (B,S,H*D) bf16
    attn_kernel<<<dim3(S_ / 64, H_, B_), 256, 0, stream>>>(q_r, k_r, v_t, mask, ctx);

    // 4. Output projection: (B*S, H*D) @ W_o^T -> (B*S, HID) fp32
    gemm_bt<true><<<dim3(HID_ / 128, (B_ * S_) / 128), 256, 0, stream>>>(
        ctx, Wo_bf, out, B_ * S_, HID_, H_ * D_);
}

// Round 4
// 893.012 us; speedup vs baseline: 1.0214x; 1.0214x over previous
//
#include <hip/hip_runtime.h>

#define B_   2
#define S_   2048
#define H_   32
#define D_   64
#define HID_ 2048

typedef unsigned short ushort_t;
typedef __attribute__((ext_vector_type(8))) short short8;
typedef __attribute__((ext_vector_type(4))) float floatx4;
typedef __attribute__((ext_vector_type(4))) unsigned short ushort4v;

typedef const __attribute__((address_space(1))) char* gas_ptr;
typedef __attribute__((address_space(3))) char* las_ptr;

__device__ __forceinline__ float bf2f(ushort_t u) {
    union { unsigned int i; float f; } v; v.i = ((unsigned int)u) << 16; return v.f;
}
__device__ __forceinline__ ushort_t f2bf(float f) {
    union { float f; unsigned int i; } v; v.f = f;
    unsigned int x = v.i;
    unsigned int r = x + 0x7fffu + ((x >> 16) & 1u);
    return (ushort_t)(r >> 16);
}

// fp32 -> bf16 cast, 8 elements/thread.
__global__ __launch_bounds__(256) void cast_f32_bf16(const float* __restrict__ in,
                                                     ushort_t* __restrict__ out,
                                                     int n8) {
    int i = blockIdx.x * 256 + threadIdx.x;
    if (i >= n8) return;
    const float4* p = (const float4*)(in + (size_t)i * 8);
    float4 a = p[0], b = p[1];
    short8 o;
    o[0] = (short)f2bf(a.x); o[1] = (short)f2bf(a.y);
    o[2] = (short)f2bf(a.z); o[3] = (short)f2bf(a.w);
    o[4] = (short)f2bf(b.x); o[5] = (short)f2bf(b.y);
    o[6] = (short)f2bf(b.z); o[7] = (short)f2bf(b.w);
    *(short8*)(out + (size_t)i * 8) = o;
}

// Pack int32 bool mask -> bitmask, 1 bit per element. bit i of out[w] = mask[w*64+i].
__global__ __launch_bounds__(256) void mask_pack(const int* __restrict__ m,
                                                 unsigned long long* __restrict__ bits) {
    int idx = blockIdx.x * 256 + threadIdx.x;
    unsigned long long bal = __ballot(m[idx] != 0);
    if ((threadIdx.x & 63) == 0) bits[idx >> 6] = bal;
}

// C = A @ B^T.  A: M x K bf16 row-major, B: N x K bf16 row-major.
// 128x128 tile, BK=32, global_load_lds width-16 staging, XOR-swizzled flat LDS.
template <bool OF32>
__global__ __launch_bounds__(256) void gemm_bt(const ushort_t* __restrict__ A,
                                               const ushort_t* __restrict__ Bm,
                                               void* __restrict__ Cv,
                                               int M, int N, int K) {
    __shared__ ushort_t lA[128 * 32];
    __shared__ ushort_t lB[128 * 32];
    const int tid  = threadIdx.x;
    const int lane = tid & 63, wave = tid >> 6;
    const int quad = lane >> 4, l16 = lane & 15;
    const int wm = wave >> 1, wn = wave & 1;
    const int m0 = blockIdx.y * 128, n0 = blockIdx.x * 128;

    // staging: lane loads 16B from row (j*64 + tid>>2), global seg (tid&3)^((tid>>3)&3).
    const int srow = tid >> 2;
    const int gseg = (tid & 3) ^ ((tid >> 3) & 3);
    const ushort_t* gA = A + (size_t)(m0 + srow) * K + gseg * 8;
    const ushort_t* gB = Bm + (size_t)(n0 + srow) * K + gseg * 8;

    // fragment read: lds seg = quad ^ ((l16>>1)&3), row stride 32 elements (no pad).
    const int fseg = quad ^ ((l16 >> 1) & 3);

    floatx4 acc[4][4];
#pragma unroll
    for (int i = 0; i < 4; i++)
#pragma unroll
        for (int j = 0; j < 4; j++) acc[i][j] = (floatx4){0.f, 0.f, 0.f, 0.f};

    for (int k0 = 0; k0 < K; k0 += 32) {
#pragma unroll
        for (int j = 0; j < 2; j++) {
            __builtin_amdgcn_global_load_lds(
                (gas_ptr)(gA + (size_t)j * 64 * K + k0),
                (las_ptr)(lA + j * 2048 + wave * 512), 16, 0, 0);
            __builtin_amdgcn_global_load_lds(
                (gas_ptr)(gB + (size_t)j * 64 * K + k0),
                (las_ptr)(lB + j * 2048 + wave * 512), 16, 0, 0);
        }
        __syncthreads();

        short8 aF[4], bF[4];
#pragma unroll
        for (int mi = 0; mi < 4; mi++)
            aF[mi] = *(const short8*)&lA[(wm * 64 + mi * 16 + l16) * 32 + fseg * 8];
#pragma unroll
        for (int ni = 0; ni < 4; ni++)
            bF[ni] = *(const short8*)&lB[(wn * 64 + ni * 16 + l16) * 32 + fseg * 8];
#pragma unroll
        for (int mi = 0; mi < 4; mi++)
#pragma unroll
            for (int ni = 0; ni < 4; ni++)
                acc[mi][ni] = __builtin_amdgcn_mfma_f32_16x16x32_bf16(aF[mi], bF[ni], acc[mi][ni], 0, 0, 0);
        __syncthreads();
    }

#pragma unroll
    for (int mi = 0; mi < 4; mi++)
#pragma unroll
        for (int ni = 0; ni < 4; ni++)
#pragma unroll
            for (int r = 0; r < 4; r++) {
                int row = m0 + wm * 64 + mi * 16 + quad * 4 + r;
                int col = n0 + wn * 64 + ni * 16 + l16;
                if (OF32) ((float*)Cv)[(size_t)row * N + col] = acc[mi][ni][r];
                else      ((ushort_t*)Cv)[(size_t)row * N + col] = f2bf(acc[mi][ni][r]);
            }
}

// qkv: (B,S,H,3D) bf16 -> q_rot, k_rot as (B,H,S,D) bf16.
__global__ __launch_bounds__(256) void rope_qk(const ushort_t* __restrict__ qkv,
                                               const int* __restrict__ pos,
                                               ushort_t* __restrict__ qr,
                                               ushort_t* __restrict__ kr) {
    int idx = blockIdx.x * 256 + threadIdx.x;   // (b,h,s,d): d fastest
    int d = idx & 63;
    int s = (idx >> 6) & 2047;
    int h = (idx >> 17) & 31;
    int b = idx >> 22;
    size_t qbase = ((size_t)(b * S_ + s)) * (3 * H_ * D_) + h * (3 * D_);
    int i  = d & 31;
    int d2 = d ^ 32;
    float x   = bf2f(qkv[qbase + d]);
    float xp  = bf2f(qkv[qbase + d2]);
    float kx  = bf2f(qkv[qbase + 64 + d]);
    float kxp = bf2f(qkv[qbase + 64 + d2]);
    int   p   = pos[b * S_ + s];
    float inv = 1.0f / powf(10000.0f, (float)(2 * i) / 64.0f);
    float t   = (float)p * inv;
    float c = cosf(t), sn = sinf(t);
    float rq = (d < 32) ? -xp : xp;
    float rk = (d < 32) ? -kxp : kxp;
    float qo = x * c + rq * sn;
    float ko = kx * c + rk * sn;
    size_t o = ((size_t)(b * H_ + h) * S_ + s) * D_ + d;
    qr[o] = f2bf(qo);
    kr[o] = f2bf(ko);
}

// v transpose: qkv (B,S,H,3D) -> vt (B,H,D,S).
__global__ __launch_bounds__(256) void v_trans(const ushort_t* __restrict__ qkv,
                                               ushort_t* __restrict__ vt) {
    int idx = blockIdx.x * 256 + threadIdx.x;   // (b,h,d,s): s fastest
    int s = idx & 2047;
    int d = (idx >> 11) & 63;
    int h = (idx >> 17) & 31;
    int b = idx >> 22;
    vt[idx] = qkv[((size_t)(b * S_ + s)) * (3 * H_ * D_) + h * (3 * D_) + 128 + d];
}

// Flash attention, transposed-score variant.
// qr,kr: (B,H,S,D); vt: (B,H,D,S); mbits: (B,S,S/64) bitmask; ctx: (B,S,H*D) bf16.
// 4 waves/block, each wave owns 16 q rows (q = l16), NO barriers (per-wave LDS).
__global__ __launch_bounds__(256) void attn_kernel(const ushort_t* __restrict__ qr,
                                                   const ushort_t* __restrict__ kr,
                                                   const ushort_t* __restrict__ vt,
                                                   const unsigned long long* __restrict__ mbits,
                                                   ushort_t* __restrict__ ctx) {
    __shared__ ushort_t lds_p[4][16][72];   // per-wave P tile [q=16][k=64 (+8 pad)]
    const int tid  = threadIdx.x;
    const int wave = tid >> 6, lane = tid & 63;
    const int quad = lane >> 4, l16 = lane & 15;
    const int b = blockIdx.z, h = blockIdx.y;
    const int q0 = blockIdx.x * 64 + wave * 16;
    const size_t headBase = ((size_t)(b * H_ + h)) * S_ * D_;
    const unsigned long long* mrow = mbits + ((size_t)b * S_ + q0 + l16) * (S_ / 64);

    // Q as B-operand: B[n=q(l16)][kdim=d]
    short8 qf[2];
#pragma unroll
    for (int ks = 0; ks < 2; ks++)
        qf[ks] = *(const short8*)(qr + headBase + (size_t)(q0 + l16) * D_ + ks * 32 + quad * 8);

    float m_st = -1e30f, l_st = 0.f;
    floatx4 o[4];
#pragma unroll
    for (int t = 0; t < 4; t++) o[t] = (floatx4){0.f, 0.f, 0.f, 0.f};

    for (int k0 = 0; k0 < S_; k0 += 64) {
        unsigned long long mb = mrow[k0 >> 6];

        // S^T tile: scT[t] rows = k-local (t*16+quad*4+r), col = q (l16)
        floatx4 scT[4];
#pragma unroll
        for (int t = 0; t < 4; t++) scT[t] = (floatx4){0.f, 0.f, 0.f, 0.f};
#pragma unroll
        for (int t = 0; t < 4; t++) {
            const ushort_t* kp = kr + headBase + (size_t)(k0 + t * 16 + l16) * D_;
            short8 kf0 = *(const short8*)(kp + quad * 8);
            short8 kf1 = *(const short8*)(kp + 32 + quad * 8);
            scT[t] = __builtin_amdgcn_mfma_f32_16x16x32_bf16(kf0, qf[0], scT[t], 0, 0, 0);
            scT[t] = __builtin_amdgcn_mfma_f32_16x16x32_bf16(kf1, qf[1], scT[t], 0, 0, 0);
        }

        // scale + mask + column max (in-lane then 2 shuffles across quads)
        float pv[4][4];
        float rm = -1e30f;
#pragma unroll
        for (int t = 0; t < 4; t++)
#pragma unroll
            for (int r = 0; r < 4; r++) {
                float v = scT[t][r] * 0.125f;
                int kl = t * 16 + quad * 4 + r;
                v = ((mb >> kl) & 1ull) ? -10000.0f : v;
                pv[t][r] = v;
                rm = fmaxf(rm, v);
            }
        rm = fmaxf(rm, __shfl_xor(rm, 16));
        rm = fmaxf(rm, __shfl_xor(rm, 32));

        float mn = fmaxf(m_st, rm);
        float alpha = __expf(m_st - mn);
        m_st = mn;

        float rs = 0.f;
#pragma unroll
        for (int t = 0; t < 4; t++)
#pragma unroll
            for (int r = 0; r < 4; r++) { pv[t][r] = __expf(pv[t][r] - mn); rs += pv[t][r]; }
        rs += __shfl_xor(rs, 16);
        rs += __shfl_xor(rs, 32);
        l_st = l_st * alpha + rs;

        // P row q=l16: per t, 4 contiguous k-slots -> one b64 write
#pragma unroll
        for (int t = 0; t < 4; t++) {
            ushort4v w;
            w[0] = f2bf(pv[t][0]); w[1] = f2bf(pv[t][1]);
            w[2] = f2bf(pv[t][2]); w[3] = f2bf(pv[t][3]);
            *(ushort4v*)&lds_p[wave][l16][t * 16 + quad * 4] = w;
        }

        // rescale O (rows q = quad*4+r need alpha of that column)
        float a_r[4];
#pragma unroll
        for (int r = 0; r < 4; r++) a_r[r] = __shfl(alpha, quad * 4 + r, 16);
#pragma unroll
        for (int t = 0; t < 4; t++)
#pragma unroll
            for (int r = 0; r < 4; r++) o[t][r] *= a_r[r];

        // P as A-operand: A[m=q(l16)][k]
        short8 pf0 = *(const short8*)&lds_p[wave][l16][quad * 8];
        short8 pf1 = *(const short8*)&lds_p[wave][l16][32 + quad * 8];

#pragma unroll
        for (int t = 0; t < 4; t++) {
            const ushort_t* vp = vt + headBase + (size_t)(t * 16 + l16) * S_ + k0;
            short8 vf0 = *(const short8*)(vp + quad * 8);
            short8 vf1 = *(const short8*)(vp + 32 + quad * 8);
            o[t] = __builtin_amdgcn_mfma_f32_16x16x32_bf16(pf0, vf0, o[t], 0, 0, 0);
            o[t] = __builtin_amdgcn_mfma_f32_16x16x32_bf16(pf1, vf1, o[t], 0, 0, 0);
        }
    }

    float li[4];
#pragma unroll
    for (int r = 0; r < 4; r++) li[r] = 1.0f / __shfl(l_st, quad * 4 + r, 16);
#pragma unroll
    for (int t = 0; t < 4; t++)
#pragma unroll
        for (int r = 0; r < 4; r++) {
            int srow = q0 + quad * 4 + r;
            ctx[((size_t)(b * S_) + srow) * (H_ * D_) + h * D_ + t * 16 + l16] = f2bf(o[t][r] * li[r]);
        }
}

extern "C" void kernel_launch(void* const* d_in, const int* in_sizes, int n_in,
                              void* d_out, int out_size, void* d_ws, size_t ws_size,
                              hipStream_t stream) {
    const float* hidden          = (const float*)d_in[0];      // fp32 (B,S,HID)
    const int* mask              = (const int*)d_in[1];        // bool -> int32
    const int* pos               = (const int*)d_in[2];        // int32
    const float* Wqkv            = (const float*)d_in[3];      // fp32 (3HD, HID)
    const float* Wo              = (const float*)d_in[4];      // fp32 (HID, HD)
    float* out                   = (float*)d_out;              // fp32 (B,S,HID)

    char* ws = (char*)d_ws;
    // layout (bytes):
    //   qkv     [0,          50331648)   bf16 (B,S,H,3D); dead after rope/v_trans
    //   ctx     [0,          16777216)   reuse qkv
    //   mbits   [16777216,   17825792)   reuse qkv (written after rope/v_trans)
    //   Wo_bf   [50331648,   58720256)
    //   hid_bf  [58720256,   75497472)   dead after QKV gemm -> q_r
    //   Wqkv_bf [75497472,  100663296)   dead after QKV gemm -> k_r
    //   v_t     [92274688,  109051904)
    ushort_t* qkv     = (ushort_t*)(ws);
    ushort_t* ctx     = (ushort_t*)(ws);
    unsigned long long* mbits = (unsigned long long*)(ws + 16777216);
    ushort_t* Wo_bf   = (ushort_t*)(ws + 50331648);
    ushort_t* hid_bf  = (ushort_t*)(ws + 58720256);
    ushort_t* Wqkv_bf = (ushort_t*)(ws + 75497472);
    ushort_t* q_r     = (ushort_t*)(ws + 58720256);
    ushort_t* k_r     = (ushort_t*)(ws + 75497472);
    ushort_t* v_t     = (ushort_t*)(ws + 92274688);

    // 0. casts fp32 -> bf16
    {
        int n8 = (B_ * S_ * HID_) / 8;
        cast_f32_bf16<<<n8 / 256, 256, 0, stream>>>(hidden, hid_bf, n8);
        n8 = (3 * H_ * D_ * HID_) / 8;
        cast_f32_bf16<<<n8 / 256, 256, 0, stream>>>(Wqkv, Wqkv_bf, n8);
        n8 = (HID_ * H_ * D_) / 8;
        cast_f32_bf16<<<n8 / 256, 256, 0, stream>>>(Wo, Wo_bf, n8);
    }

    // 1. QKV projection: (B*S, HID) @ W_qkv^T -> (B*S, 3*H*D) bf16
    gemm_bt<false><<<dim3((3 * H_ * D_) / 128, (B_ * S_) / 128), 256, 0, stream>>>(
        hid_bf, Wqkv_bf, qkv, B_ * S_, 3 * H_ * D_, HID_);

    // 2. RoPE (q,k) + v transpose
    int nElem = B_ * H_ * S_ * D_;
    rope_qk<<<nElem / 256, 256, 0, stream>>>(qkv, pos, q_r, k_r);
    v_trans<<<nElem / 256, 256, 0, stream>>>(qkv, v_t);

    // 2b. pack mask bits (qkv region now dead)
    mask_pack<<<(B_ * S_ * S_) / 256, 256, 0, stream>>>(mask, mbits);

    // 3. Flash attention -> ctx (B,S,H*D) bf16
    attn_kernel<<<dim3(S_ / 64, H_, B_), 256, 0, stream>>>(q_r, k_r, v_t, mbits, ctx);

    // 4. Output projection: (B*S, H*D) @ W_o^T -> (B*S, HID) fp32
    gemm_bt<true><<<dim3(HID_ / 128, (B_ * S_) / 128), 256, 0, stream>>>(
        ctx, Wo_bf, out, B_ * S_, HID_, H_ * D_);
}